// Round 4
// baseline (522.629 us; speedup 1.0000x reference)
//
#include <hip/hip_runtime.h>
#include <hip/hip_bf16.h>

typedef unsigned short u16;
typedef unsigned int u32;
typedef short bf16x8 __attribute__((ext_vector_type(8)));
typedef float f32x4 __attribute__((ext_vector_type(4)));

#define LOG2E 1.4426950408889634f

// Problem constants: B=2, L=2048, D=1024, H=16, hd=64, INNER=4096
#define SEQ 2048
#define DM 1024
#define NH 16
#define HD 64
#define INNER 4096
#define MTOT 4096  // B*L
#define QKV_ELEMS 4194304  // 2*16*2048*64

static __device__ __forceinline__ u16 f2bf(float f) {
  u32 u = __float_as_uint(f);
  u = (u + 0x7fffu + ((u >> 16) & 1u)) >> 16;
  return (u16)u;
}

static __device__ __forceinline__ void async_copy16(void* lds, const void* g) {
  __builtin_amdgcn_global_load_lds(
      (const __attribute__((address_space(1))) u32*)g,
      (__attribute__((address_space(3))) u32*)lds, 16, 0, 0);
}

#define MFMA16(a, b, c) __builtin_amdgcn_mfma_f32_16x16x32_bf16(a, b, c, 0, 0, 0)

// ---------------- transpose + fp32->bf16 cast: dst[n][k] = bf16(src[k][n]) ----
__global__ __launch_bounds__(256) void transpose_cast(
    const float* __restrict__ src, u16* __restrict__ dst, int K, int N) {
  __shared__ float tile[32][33];
  int bx = blockIdx.x;  // along N
  int by = blockIdx.y;  // along K
  int t = threadIdx.x;
  int tr = t >> 5, tc = t & 31;
#pragma unroll
  for (int i = 0; i < 4; ++i) {
    int r = by * 32 + tr + i * 8;
    int c = bx * 32 + tc;
    tile[tr + i * 8][tc] = src[(size_t)r * N + c];
  }
  __syncthreads();
#pragma unroll
  for (int i = 0; i < 4; ++i) {
    int n = bx * 32 + tr + i * 8;
    int kk = by * 32 + tc;
    dst[(size_t)n * K + kk] = f2bf(tile[tc][tr + i * 8]);
  }
}

// ---------------- LayerNorm (fp32 in, bf16 out), one row per block ----------
__global__ __launch_bounds__(256) void ln_kernel(
    const float* __restrict__ x, const float* __restrict__ g,
    const float* __restrict__ b, u16* __restrict__ out) {
  int row = blockIdx.x, t = threadIdx.x;
  const float* xr = x + (size_t)row * DM;
  float4 v = *(const float4*)(xr + t * 4);
  float s = v.x + v.y + v.z + v.w;
  float ss = v.x * v.x + v.y * v.y + v.z * v.z + v.w * v.w;
#pragma unroll
  for (int d = 1; d < 64; d <<= 1) {
    s += __shfl_xor(s, d);
    ss += __shfl_xor(ss, d);
  }
  __shared__ float red[8];
  int w = t >> 6, lane = t & 63;
  if (lane == 0) { red[w] = s; red[4 + w] = ss; }
  __syncthreads();
  s = red[0] + red[1] + red[2] + red[3];
  ss = red[4] + red[5] + red[6] + red[7];
  float mu = s * (1.f / DM);
  float var = ss * (1.f / DM) - mu * mu;
  float rstd = rsqrtf(var + 1e-5f);
  float4 gv = *(const float4*)(g + t * 4);
  float4 bv = *(const float4*)(b + t * 4);
  u32 p0 = (u32)f2bf((v.x - mu) * rstd * gv.x + bv.x) |
           ((u32)f2bf((v.y - mu) * rstd * gv.y + bv.y) << 16);
  u32 p1 = (u32)f2bf((v.z - mu) * rstd * gv.z + bv.z) |
           ((u32)f2bf((v.w - mu) * rstd * gv.w + bv.w) << 16);
  uint2 pk; pk.x = p0; pk.y = p1;
  *(uint2*)(out + (size_t)row * DM + t * 4) = pk;
}

// ---------------- GEMM: C[M][N] = A[M][K] (bf16) @ Bt[N][K]^T (bf16) --------
// 128x128 tile, BK=32, 4 waves (2x2), each wave 64x64 = 4x4 16x16 frags.
// EPI 0: +bias, scatter to q(x0.125*log2e)/k/(v transposed) bf16
// EPI 1: +bias +resid -> fp32
// EPI 2: +bias, exact GELU -> bf16
template <int EPI>
__global__ __launch_bounds__(256) void gemm_bt(
    const u16* __restrict__ A, const u16* __restrict__ Bt,
    const float* __restrict__ bias, const float* __restrict__ resid,
    void* __restrict__ outp, int M, int N, int K) {
  __shared__ u16 As[128 * 32];
  __shared__ u16 Bs[128 * 32];
  int t = threadIdx.x;
  int lane = t & 63, w = t >> 6;
  int lo = lane & 15, hi = lane >> 4;
  int wr = w >> 1, wc = w & 1;
  int m0 = blockIdx.y * 128, n0 = blockIdx.x * 128;

  f32x4 acc[4][4];
#pragma unroll
  for (int i = 0; i < 4; ++i)
#pragma unroll
    for (int j = 0; j < 4; ++j) acc[i][j] = f32x4{0.f, 0.f, 0.f, 0.f};

  const u16* gA = A + (size_t)(m0 + (t >> 2)) * K + (t & 3) * 8;
  const u16* gB = Bt + (size_t)(n0 + (t >> 2)) * K + (t & 3) * 8;
  char* lA = (char*)As + (t >> 6) * 1024;
  char* lB = (char*)Bs + (t >> 6) * 1024;

  for (int kt = 0; kt < K; kt += 32) {
    async_copy16(lA, gA + kt);
    async_copy16(lA + 4096, gA + (size_t)64 * K + kt);
    async_copy16(lB, gB + kt);
    async_copy16(lB + 4096, gB + (size_t)64 * K + kt);
    __syncthreads();
    bf16x8 af[4], bf[4];
#pragma unroll
    for (int f = 0; f < 4; ++f)
      af[f] = *(const bf16x8*)(As + (wr * 64 + f * 16 + lo) * 32 + hi * 8);
#pragma unroll
    for (int f = 0; f < 4; ++f)
      bf[f] = *(const bf16x8*)(Bs + (wc * 64 + f * 16 + lo) * 32 + hi * 8);
#pragma unroll
    for (int i = 0; i < 4; ++i)
#pragma unroll
      for (int j = 0; j < 4; ++j)
        acc[i][j] = MFMA16(af[i], bf[j], acc[i][j]);
    __syncthreads();
  }

#pragma unroll
  for (int i = 0; i < 4; ++i) {
#pragma unroll
    for (int j = 0; j < 4; ++j) {
      int col = n0 + wc * 64 + j * 16 + lo;
#pragma unroll
      for (int r = 0; r < 4; ++r) {
        int m = m0 + wr * 64 + i * 16 + hi * 4 + r;
        float val = acc[i][j][r];
        if constexpr (EPI == 0) {
          val += bias[col];
          int which = col >> 10;
          int h = (col >> 6) & 15, d = col & 63;
          int b = m >> 11, l = m & 2047;
          size_t bh = (size_t)(b * NH + h);
          u16* qp = (u16*)outp;
          if (which == 0)
            qp[(bh * SEQ + l) * HD + d] = f2bf(val * 0.18033688011112043f);
          else if (which == 1)
            (qp + QKV_ELEMS)[(bh * SEQ + l) * HD + d] = f2bf(val);
          else
            (qp + 2 * QKV_ELEMS)[(bh * HD + d) * SEQ + l] = f2bf(val);
        } else if constexpr (EPI == 1) {
          val += bias[col] + resid[(size_t)m * N + col];
          ((float*)outp)[(size_t)m * N + col] = val;
        } else {
          val += bias[col];
          val = 0.5f * val * (1.0f + erff(val * 0.7071067811865476f));
          ((u16*)outp)[(size_t)m * N + col] = f2bf(val);
        }
      }
    }
  }
}

// ---------------- causal flash attention (barrier-free, LDS-free K/V) -------
// 1 wave per block. Each wave owns one 16-row q-strip. K/V fragments are read
// directly from global (L2-resident: 512KB per bh). XCD-aware decode keeps all
// strips of a bh on one XCD (4 bh x 512KB = 2MB < 4MB L2/XCD). Heavy strips
// dispatched first. q is pre-scaled by 0.125*log2e; softmax in exp2 domain.
// v is stored transposed: vt[bh][d][l]. Only LDS: per-wave 16x72 P repack.
__global__ __launch_bounds__(64) void attn_kernel(
    const u16* __restrict__ q, const u16* __restrict__ k,
    const u16* __restrict__ vt, u16* __restrict__ o) {
  int wgid = blockIdx.x;      // 4096 = 8 xcd * 128 strips * 4 bh-groups
  int xcd = wgid & 7;
  int j = wgid >> 3;          // [0, 512)
  int strip = 127 - (j & 127);  // heavy strips first
  int bh = (j >> 7) * 8 + xcd;  // [0, 32), grouped per XCD
  int lane = threadIdx.x;
  int lo = lane & 15, hi = lane >> 4;

  __shared__ u16 Ps[16][72];

  const u16* kg = k + (size_t)bh * SEQ * HD;
  const u16* vg = vt + (size_t)bh * HD * SEQ;
  int b = bh >> 4, h = bh & 15;

  int qrow = strip * 16 + lo;
  const u16* qbase = q + ((size_t)bh * SEQ + qrow) * HD;
  bf16x8 qf0 = *(const bf16x8*)(qbase + hi * 8);
  bf16x8 qf1 = *(const bf16x8*)(qbase + 32 + hi * 8);

  f32x4 o_acc[4];
#pragma unroll
  for (int df = 0; df < 4; ++df) o_acc[df] = f32x4{0.f, 0.f, 0.f, 0.f};
  float m_run[4] = {-INFINITY, -INFINITY, -INFINITY, -INFINITY};
  float s_run[4] = {0.f, 0.f, 0.f, 0.f};

  int ktmax = strip >> 2;
  for (int kt = 0; kt <= ktmax; ++kt) {
    // S = Q K^T (16 q-rows x 64 k), K frags direct from global
    f32x4 s[4];
#pragma unroll
    for (int cf = 0; cf < 4; ++cf) {
      const u16* kr = kg + (size_t)(kt * 64 + cf * 16 + lo) * HD + hi * 8;
      bf16x8 kf0 = *(const bf16x8*)(kr);
      bf16x8 kf1 = *(const bf16x8*)(kr + 32);
      s[cf] = f32x4{0.f, 0.f, 0.f, 0.f};
      s[cf] = MFMA16(qf0, kf0, s[cf]);
      s[cf] = MFMA16(qf1, kf1, s[cf]);
    }

    if (kt == ktmax) {
#pragma unroll
      for (int cf = 0; cf < 4; ++cf)
#pragma unroll
        for (int r = 0; r < 4; ++r) {
          int kcol = kt * 64 + cf * 16 + lo;
          int qr = strip * 16 + hi * 4 + r;
          if (kcol > qr) s[cf][r] = -INFINITY;
        }
    }

    float alpha[4];
#pragma unroll
    for (int r = 0; r < 4; ++r) {
      float v = fmaxf(fmaxf(s[0][r], s[1][r]), fmaxf(s[2][r], s[3][r]));
      v = fmaxf(v, __shfl_xor(v, 1));
      v = fmaxf(v, __shfl_xor(v, 2));
      v = fmaxf(v, __shfl_xor(v, 4));
      v = fmaxf(v, __shfl_xor(v, 8));
      float mnew = fmaxf(m_run[r], v);
      float a = exp2f(m_run[r] - mnew);
      m_run[r] = mnew;
      float psum = 0.f;
#pragma unroll
      for (int cf = 0; cf < 4; ++cf) {
        float p = exp2f(s[cf][r] - mnew);
        Ps[hi * 4 + r][cf * 16 + lo] = f2bf(p);
        psum += p;
      }
      psum += __shfl_xor(psum, 1);
      psum += __shfl_xor(psum, 2);
      psum += __shfl_xor(psum, 4);
      psum += __shfl_xor(psum, 8);
      s_run[r] = s_run[r] * a + psum;
      alpha[r] = a;
    }
#pragma unroll
    for (int df = 0; df < 4; ++df)
#pragma unroll
      for (int r = 0; r < 4; ++r) o_acc[df][r] *= alpha[r];

    // O += P V   (P: 16x64 from LDS repack, V^T frags direct from global)
#pragma unroll
    for (int ks = 0; ks < 2; ++ks) {
      bf16x8 pf = *(const bf16x8*)&Ps[lo][ks * 32 + hi * 8];
#pragma unroll
      for (int df = 0; df < 4; ++df) {
        const u16* vr =
            vg + (size_t)(df * 16 + lo) * SEQ + kt * 64 + ks * 32 + hi * 8;
        bf16x8 vf = *(const bf16x8*)vr;
        o_acc[df] = MFMA16(pf, vf, o_acc[df]);
      }
    }
  }

#pragma unroll
  for (int df = 0; df < 4; ++df) {
#pragma unroll
    for (int r = 0; r < 4; ++r) {
      float val = o_acc[df][r] / s_run[r];
      int orow = strip * 16 + hi * 4 + r;
      size_t oidx = ((size_t)b * SEQ + orow) * DM + h * HD + df * 16 + lo;
      o[oidx] = f2bf(val);
    }
  }
}

// ---------------- launch ----------------------------------------------------
extern "C" void kernel_launch(void* const* d_in, const int* in_sizes, int n_in,
                              void* d_out, int out_size, void* d_ws,
                              size_t ws_size, hipStream_t stream) {
  const float* x = (const float*)d_in[0];
  const float* w_qkv = (const float*)d_in[1];
  const float* b_qkv = (const float*)d_in[2];
  const float* w_out = (const float*)d_in[3];
  const float* b_out = (const float*)d_in[4];
  const float* w_fc1 = (const float*)d_in[5];
  const float* b_fc1 = (const float*)d_in[6];
  const float* w_fc2 = (const float*)d_in[7];
  const float* b_fc2 = (const float*)d_in[8];
  const float* ln1_g = (const float*)d_in[9];
  const float* ln1_b = (const float*)d_in[10];
  const float* ln2_g = (const float*)d_in[11];
  const float* ln2_b = (const float*)d_in[12];
  float* out = (float*)d_out;

  char* ws = (char*)d_ws;
  const size_t MB = 1u << 20;
  u16* hb = (u16*)(ws + 0);            // 8 MB (LN1 out, reused for LN2 out)
  u16* wqkvT = (u16*)(ws + 8 * MB);    // 6 MB
  u16* woutT = (u16*)(ws + 14 * MB);   // 2 MB
  u16* wfc1T = (u16*)(ws + 16 * MB);   // 8 MB
  u16* wfc2T = (u16*)(ws + 24 * MB);   // 8 MB
  u16* qb = (u16*)(ws + 32 * MB);      // q 8MB, k 8MB, vt 8MB contiguous
  u16* attn_o = (u16*)(ws + 56 * MB);  // 8 MB
  float* x1 = (float*)(ws + 64 * MB);  // 16 MB
  u16* gbuf = (u16*)(ws + 32 * MB);    // 32 MB, aliases q/k/vt/attn_o (dead)

  dim3 blk(256);

  // weights -> bf16, transposed
  transpose_cast<<<dim3(3072 / 32, 1024 / 32), blk, 0, stream>>>(w_qkv, wqkvT, 1024, 3072);
  transpose_cast<<<dim3(1024 / 32, 1024 / 32), blk, 0, stream>>>(w_out, woutT, 1024, 1024);
  transpose_cast<<<dim3(4096 / 32, 1024 / 32), blk, 0, stream>>>(w_fc1, wfc1T, 1024, 4096);
  transpose_cast<<<dim3(1024 / 32, 4096 / 32), blk, 0, stream>>>(w_fc2, wfc2T, 4096, 1024);

  // LN1
  ln_kernel<<<MTOT, blk, 0, stream>>>(x, ln1_g, ln1_b, hb);

  // QKV projection, scatter to q/k/vt
  gemm_bt<0><<<dim3(3072 / 128, MTOT / 128), blk, 0, stream>>>(
      hb, wqkvT, b_qkv, nullptr, qb, MTOT, 3072, 1024);

  // causal attention (barrier-free, 1 wave/block, XCD-grouped)
  attn_kernel<<<dim3(4096), dim3(64), 0, stream>>>(
      qb, qb + QKV_ELEMS, qb + 2 * QKV_ELEMS, attn_o);

  // out projection + residual -> x1 (fp32)
  gemm_bt<1><<<dim3(1024 / 128, MTOT / 128), blk, 0, stream>>>(
      attn_o, woutT, b_out, x, x1, MTOT, 1024, 1024);

  // LN2
  ln_kernel<<<MTOT, blk, 0, stream>>>(x1, ln2_g, ln2_b, hb);

  // FC1 + GELU -> bf16
  gemm_bt<2><<<dim3(4096 / 128, MTOT / 128), blk, 0, stream>>>(
      hb, wfc1T, b_fc1, nullptr, gbuf, MTOT, 4096, 1024);

  // FC2 + residual -> out (fp32)
  gemm_bt<1><<<dim3(1024 / 128, MTOT / 128), blk, 0, stream>>>(
      gbuf, wfc2T, b_fc2, x1, out, MTOT, 1024, 4096);
}

// Round 5
// 430.569 us; speedup vs baseline: 1.2138x; 1.2138x over previous
//
#include <hip/hip_runtime.h>
#include <hip/hip_bf16.h>

typedef unsigned short u16;
typedef unsigned int u32;
typedef short bf16x8 __attribute__((ext_vector_type(8)));
typedef float f32x4 __attribute__((ext_vector_type(4)));

// Problem constants: B=2, L=2048, D=1024, H=16, hd=64, INNER=4096
#define SEQ 2048
#define DM 1024
#define NH 16
#define HD 64
#define INNER 4096
#define MTOT 4096  // B*L
#define QKV_ELEMS 4194304  // 2*16*2048*64

static __device__ __forceinline__ u16 f2bf(float f) {
  u32 u = __float_as_uint(f);
  u = (u + 0x7fffu + ((u >> 16) & 1u)) >> 16;
  return (u16)u;
}

static __device__ __forceinline__ void async_copy16(void* lds, const void* g) {
  __builtin_amdgcn_global_load_lds(
      (const __attribute__((address_space(1))) u32*)g,
      (__attribute__((address_space(3))) u32*)lds, 16, 0, 0);
}

#define MFMA16(a, b, c) __builtin_amdgcn_mfma_f32_16x16x32_bf16(a, b, c, 0, 0, 0)

// ---------------- transpose + fp32->bf16 cast: dst[n][k] = bf16(src[k][n]) ----
__global__ __launch_bounds__(256) void transpose_cast(
    const float* __restrict__ src, u16* __restrict__ dst, int K, int N) {
  __shared__ float tile[32][33];
  int bx = blockIdx.x;  // along N
  int by = blockIdx.y;  // along K
  int t = threadIdx.x;
  int tr = t >> 5, tc = t & 31;
#pragma unroll
  for (int i = 0; i < 4; ++i) {
    int r = by * 32 + tr + i * 8;
    int c = bx * 32 + tc;
    tile[tr + i * 8][tc] = src[(size_t)r * N + c];
  }
  __syncthreads();
#pragma unroll
  for (int i = 0; i < 4; ++i) {
    int n = bx * 32 + tr + i * 8;
    int kk = by * 32 + tc;
    dst[(size_t)n * K + kk] = f2bf(tile[tc][tr + i * 8]);
  }
}

// ---------------- LayerNorm (fp32 in, bf16 out), one row per block ----------
__global__ __launch_bounds__(256) void ln_kernel(
    const float* __restrict__ x, const float* __restrict__ g,
    const float* __restrict__ b, u16* __restrict__ out) {
  int row = blockIdx.x, t = threadIdx.x;
  const float* xr = x + (size_t)row * DM;
  float4 v = *(const float4*)(xr + t * 4);
  float s = v.x + v.y + v.z + v.w;
  float ss = v.x * v.x + v.y * v.y + v.z * v.z + v.w * v.w;
#pragma unroll
  for (int d = 1; d < 64; d <<= 1) {
    s += __shfl_xor(s, d);
    ss += __shfl_xor(ss, d);
  }
  __shared__ float red[8];
  int w = t >> 6, lane = t & 63;
  if (lane == 0) { red[w] = s; red[4 + w] = ss; }
  __syncthreads();
  s = red[0] + red[1] + red[2] + red[3];
  ss = red[4] + red[5] + red[6] + red[7];
  float mu = s * (1.f / DM);
  float var = ss * (1.f / DM) - mu * mu;
  float rstd = rsqrtf(var + 1e-5f);
  float4 gv = *(const float4*)(g + t * 4);
  float4 bv = *(const float4*)(b + t * 4);
  u32 p0 = (u32)f2bf((v.x - mu) * rstd * gv.x + bv.x) |
           ((u32)f2bf((v.y - mu) * rstd * gv.y + bv.y) << 16);
  u32 p1 = (u32)f2bf((v.z - mu) * rstd * gv.z + bv.z) |
           ((u32)f2bf((v.w - mu) * rstd * gv.w + bv.w) << 16);
  uint2 pk; pk.x = p0; pk.y = p1;
  *(uint2*)(out + (size_t)row * DM + t * 4) = pk;
}

// ---------------- GEMM: C[M][N] = A[M][K] (bf16) @ Bt[N][K]^T (bf16) --------
// 128xBN tile (BN=128 or 64), BK=32, 4 waves (2x2). Per-wave output:
// 64 x (BN/2) = 4 x NF 16x16 frags. Double-buffered LDS, 2-phase prefetch:
// issue next K-tile's global_load_lds BEFORE computing current tile; the
// single trailing __syncthreads (vmcnt drain) lands after MFMA cover.
// EPI 0: +bias, scatter to q(x0.125*log2e)/k/(v transposed) bf16
// EPI 1: +bias +resid -> fp32
// EPI 2: +bias, exact GELU -> bf16
template <int EPI, int BN>
__global__ __launch_bounds__(256) void gemm_bt(
    const u16* __restrict__ A, const u16* __restrict__ Bt,
    const float* __restrict__ bias, const float* __restrict__ resid,
    void* __restrict__ outp, int M, int N, int K) {
  constexpr int NF = BN / 32;  // N-frags per wave (2x2 wave grid)
  __shared__ u16 As[2][128 * 32];
  __shared__ u16 Bs[2][BN * 32];
  int t = threadIdx.x;
  int lane = t & 63, w = t >> 6;
  int lo = lane & 15, hi = lane >> 4;
  int wr = w >> 1, wc = w & 1;
  int m0 = blockIdx.y * 128, n0 = blockIdx.x * BN;

  f32x4 acc[4][NF];
#pragma unroll
  for (int i = 0; i < 4; ++i)
#pragma unroll
    for (int j = 0; j < NF; ++j) acc[i][j] = f32x4{0.f, 0.f, 0.f, 0.f};

  const u16* gA = A + (size_t)(m0 + (t >> 2)) * K + (t & 3) * 8;
  const u16* gB = Bt + (size_t)(n0 + (t >> 2)) * K + (t & 3) * 8;

  auto STAGE = [&](int buf, int kt) {
    char* lA = (char*)(&As[buf][0]) + w * 1024;
    char* lB = (char*)(&Bs[buf][0]) + w * 1024;
    async_copy16(lA, gA + kt * 32);
    async_copy16(lA + 4096, gA + (size_t)64 * K + kt * 32);
    async_copy16(lB, gB + kt * 32);
    if constexpr (BN == 128)
      async_copy16(lB + 4096, gB + (size_t)64 * K + kt * 32);
  };

  int nk = K >> 5;
  int buf = 0;
  STAGE(0, 0);
  __syncthreads();  // drains vmcnt, tile 0 ready

  for (int kt = 0; kt < nk; ++kt) {
    if (kt + 1 < nk) STAGE(buf ^ 1, kt + 1);  // prefetch overlaps compute
    bf16x8 af[4], bq[NF];
#pragma unroll
    for (int f = 0; f < 4; ++f)
      af[f] = *(const bf16x8*)(&As[buf][(wr * 64 + f * 16 + lo) * 32 + hi * 8]);
#pragma unroll
    for (int j = 0; j < NF; ++j)
      bq[j] = *(const bf16x8*)(&Bs[buf][(wc * (BN / 2) + j * 16 + lo) * 32 + hi * 8]);
#pragma unroll
    for (int i = 0; i < 4; ++i)
#pragma unroll
      for (int j = 0; j < NF; ++j)
        acc[i][j] = MFMA16(af[i], bq[j], acc[i][j]);
    __syncthreads();  // one barrier/step: drains prefetch + read-write hazard
    buf ^= 1;
  }

#pragma unroll
  for (int i = 0; i < 4; ++i) {
#pragma unroll
    for (int j = 0; j < NF; ++j) {
      int col = n0 + wc * (BN / 2) + j * 16 + lo;
#pragma unroll
      for (int r = 0; r < 4; ++r) {
        int m = m0 + wr * 64 + i * 16 + hi * 4 + r;
        float val = acc[i][j][r];
        if constexpr (EPI == 0) {
          val += bias[col];
          int which = col >> 10;
          int h = (col >> 6) & 15, d = col & 63;
          int b = m >> 11, l = m & 2047;
          size_t bh = (size_t)(b * NH + h);
          u16* qp = (u16*)outp;
          if (which == 0)
            qp[(bh * SEQ + l) * HD + d] = f2bf(val * 0.18033688011112043f);
          else if (which == 1)
            (qp + QKV_ELEMS)[(bh * SEQ + l) * HD + d] = f2bf(val);
          else
            (qp + 2 * QKV_ELEMS)[(bh * HD + d) * SEQ + l] = f2bf(val);
        } else if constexpr (EPI == 1) {
          val += bias[col] + resid[(size_t)m * N + col];
          ((float*)outp)[(size_t)m * N + col] = val;
        } else {
          val += bias[col];
          val = 0.5f * val * (1.0f + erff(val * 0.7071067811865476f));
          ((u16*)outp)[(size_t)m * N + col] = f2bf(val);
        }
      }
    }
  }
}

// ---------------- causal flash attention (round-2 structure, log2 domain) ---
// Balanced: grid (16 pair-slots, 32 bh). Block bx handles q-tiles (31-bx) and
// bx sequentially -> every block does exactly 33 k-tile steps.
// 4 waves x 16 q-rows. K/V tiles (64x64 bf16) XOR-swizzled in LDS.
// q is pre-scaled by 0.125*log2e; softmax in exp2 domain.
// v is stored transposed: vt[bh][d][l].
__global__ __launch_bounds__(256) void attn_kernel(
    const u16* __restrict__ q, const u16* __restrict__ k,
    const u16* __restrict__ vt, u16* __restrict__ o) {
  int bx = blockIdx.x, bh = blockIdx.y;
  int t = threadIdx.x;
  int lane = t & 63, w = t >> 6;
  int lo = lane & 15, hi = lane >> 4;

  __shared__ u16 Ks[64 * 64];
  __shared__ u16 Vs[64 * 64];
  __shared__ u16 Ps[4][16][72];

  const u16* kg = k + (size_t)bh * SEQ * HD;
  const u16* vg = vt + (size_t)bh * HD * SEQ;
  int b = bh >> 4, h = bh & 15;

  u32 sw = (u32)((lo & 7) << 4);  // read-side XOR swizzle (row = *16+lo)

#pragma unroll 1
  for (int pass = 0; pass < 2; ++pass) {
    int qt = pass == 0 ? (31 - bx) : bx;

    int qrow = qt * 64 + w * 16 + lo;
    const u16* qbase = q + ((size_t)bh * SEQ + qrow) * HD;
    bf16x8 qf0 = *(const bf16x8*)(qbase + hi * 8);
    bf16x8 qf1 = *(const bf16x8*)(qbase + 32 + hi * 8);

    f32x4 o_acc[4];
#pragma unroll
    for (int df = 0; df < 4; ++df) o_acc[df] = f32x4{0.f, 0.f, 0.f, 0.f};
    float m_run[4] = {-INFINITY, -INFINITY, -INFINITY, -INFINITY};
    float s_run[4] = {0.f, 0.f, 0.f, 0.f};

    for (int kt = 0; kt <= qt; ++kt) {
      __syncthreads();
#pragma unroll
      for (int p = 0; p < 2; ++p) {
        int idx = p * 256 + t;
        int r = idx >> 3, c8 = (idx & 7) * 8;
        u32 off = (u32)(r * 128 + c8 * 2);
        u32 soff = off ^ (u32)((r & 7) << 4);
        *(bf16x8*)((char*)Ks + soff) =
            *(const bf16x8*)(kg + ((size_t)(kt * 64 + r)) * HD + c8);
        *(bf16x8*)((char*)Vs + soff) =
            *(const bf16x8*)(vg + (size_t)r * SEQ + kt * 64 + c8);
      }
      __syncthreads();

      // S = Q K^T (16x64 per wave)
      f32x4 s[4];
#pragma unroll
      for (int cf = 0; cf < 4; ++cf) {
        s[cf] = f32x4{0.f, 0.f, 0.f, 0.f};
        u32 ro = (u32)((cf * 16 + lo) * 128);
        bf16x8 kf0 = *(const bf16x8*)((char*)Ks + ((ro + hi * 16) ^ sw));
        bf16x8 kf1 = *(const bf16x8*)((char*)Ks + ((ro + 64 + hi * 16) ^ sw));
        s[cf] = MFMA16(qf0, kf0, s[cf]);
        s[cf] = MFMA16(qf1, kf1, s[cf]);
      }

      if (kt == qt) {
#pragma unroll
        for (int cf = 0; cf < 4; ++cf)
#pragma unroll
          for (int r = 0; r < 4; ++r) {
            int kcol = kt * 64 + cf * 16 + lo;
            int qr = qt * 64 + w * 16 + hi * 4 + r;
            if (kcol > qr) s[cf][r] = -INFINITY;
          }
      }

      float alpha[4];
#pragma unroll
      for (int r = 0; r < 4; ++r) {
        float v = fmaxf(fmaxf(s[0][r], s[1][r]), fmaxf(s[2][r], s[3][r]));
        v = fmaxf(v, __shfl_xor(v, 1));
        v = fmaxf(v, __shfl_xor(v, 2));
        v = fmaxf(v, __shfl_xor(v, 4));
        v = fmaxf(v, __shfl_xor(v, 8));
        float mnew = fmaxf(m_run[r], v);
        float a = exp2f(m_run[r] - mnew);
        m_run[r] = mnew;
        float psum = 0.f;
#pragma unroll
        for (int cf = 0; cf < 4; ++cf) {
          float p = exp2f(s[cf][r] - mnew);
          Ps[w][hi * 4 + r][cf * 16 + lo] = f2bf(p);
          psum += p;
        }
        psum += __shfl_xor(psum, 1);
        psum += __shfl_xor(psum, 2);
        psum += __shfl_xor(psum, 4);
        psum += __shfl_xor(psum, 8);
        s_run[r] = s_run[r] * a + psum;
        alpha[r] = a;
      }
#pragma unroll
      for (int df = 0; df < 4; ++df)
#pragma unroll
        for (int r = 0; r < 4; ++r) o_acc[df][r] *= alpha[r];

      // O += P V   (P: 16 x 64 from LDS, V^T tiles: rows=d, cols=kpos)
#pragma unroll
      for (int ks = 0; ks < 2; ++ks) {
        bf16x8 pf = *(const bf16x8*)&Ps[w][lo][ks * 32 + hi * 8];
#pragma unroll
        for (int df = 0; df < 4; ++df) {
          u32 ro = (u32)((df * 16 + lo) * 128);
          bf16x8 vf =
              *(const bf16x8*)((char*)Vs + ((ro + ks * 64 + hi * 16) ^ sw));
          o_acc[df] = MFMA16(pf, vf, o_acc[df]);
        }
      }
    }

#pragma unroll
    for (int df = 0; df < 4; ++df) {
#pragma unroll
      for (int r = 0; r < 4; ++r) {
        float val = o_acc[df][r] / s_run[r];
        int orow = qt * 64 + w * 16 + hi * 4 + r;
        size_t oidx = ((size_t)b * SEQ + orow) * DM + h * HD + df * 16 + lo;
        o[oidx] = f2bf(val);
      }
    }
  }
}

// ---------------- launch ----------------------------------------------------
extern "C" void kernel_launch(void* const* d_in, const int* in_sizes, int n_in,
                              void* d_out, int out_size, void* d_ws,
                              size_t ws_size, hipStream_t stream) {
  const float* x = (const float*)d_in[0];
  const float* w_qkv = (const float*)d_in[1];
  const float* b_qkv = (const float*)d_in[2];
  const float* w_out = (const float*)d_in[3];
  const float* b_out = (const float*)d_in[4];
  const float* w_fc1 = (const float*)d_in[5];
  const float* b_fc1 = (const float*)d_in[6];
  const float* w_fc2 = (const float*)d_in[7];
  const float* b_fc2 = (const float*)d_in[8];
  const float* ln1_g = (const float*)d_in[9];
  const float* ln1_b = (const float*)d_in[10];
  const float* ln2_g = (const float*)d_in[11];
  const float* ln2_b = (const float*)d_in[12];
  float* out = (float*)d_out;

  char* ws = (char*)d_ws;
  const size_t MB = 1u << 20;
  u16* hb = (u16*)(ws + 0);            // 8 MB (LN1 out, reused for LN2 out)
  u16* wqkvT = (u16*)(ws + 8 * MB);    // 6 MB
  u16* woutT = (u16*)(ws + 14 * MB);   // 2 MB
  u16* wfc1T = (u16*)(ws + 16 * MB);   // 8 MB
  u16* wfc2T = (u16*)(ws + 24 * MB);   // 8 MB
  u16* qb = (u16*)(ws + 32 * MB);      // q 8MB, k 8MB, vt 8MB contiguous
  u16* attn_o = (u16*)(ws + 56 * MB);  // 8 MB
  float* x1 = (float*)(ws + 64 * MB);  // 16 MB
  u16* gbuf = (u16*)(ws + 32 * MB);    // 32 MB, aliases q/k/vt/attn_o (dead)

  dim3 blk(256);

  // weights -> bf16, transposed
  transpose_cast<<<dim3(3072 / 32, 1024 / 32), blk, 0, stream>>>(w_qkv, wqkvT, 1024, 3072);
  transpose_cast<<<dim3(1024 / 32, 1024 / 32), blk, 0, stream>>>(w_out, woutT, 1024, 1024);
  transpose_cast<<<dim3(4096 / 32, 1024 / 32), blk, 0, stream>>>(w_fc1, wfc1T, 1024, 4096);
  transpose_cast<<<dim3(1024 / 32, 4096 / 32), blk, 0, stream>>>(w_fc2, wfc2T, 4096, 1024);

  // LN1
  ln_kernel<<<MTOT, blk, 0, stream>>>(x, ln1_g, ln1_b, hb);

  // QKV projection, scatter to q/k/vt
  gemm_bt<0, 128><<<dim3(3072 / 128, MTOT / 128), blk, 0, stream>>>(
      hb, wqkvT, b_qkv, nullptr, qb, MTOT, 3072, 1024);

  // causal attention (balanced q-tile pairing)
  attn_kernel<<<dim3(16, 32), blk, 0, stream>>>(
      qb, qb + QKV_ELEMS, qb + 2 * QKV_ELEMS, attn_o);

  // out projection + residual -> x1 (fp32)   [BN=64: 512 blocks = 2/CU]
  gemm_bt<1, 64><<<dim3(1024 / 64, MTOT / 128), blk, 0, stream>>>(
      attn_o, woutT, b_out, x, x1, MTOT, 1024, 1024);

  // LN2
  ln_kernel<<<MTOT, blk, 0, stream>>>(x1, ln2_g, ln2_b, hb);

  // FC1 + GELU -> bf16
  gemm_bt<2, 128><<<dim3(4096 / 128, MTOT / 128), blk, 0, stream>>>(
      hb, wfc1T, b_fc1, nullptr, gbuf, MTOT, 4096, 1024);

  // FC2 + residual -> out (fp32)   [BN=64: 512 blocks = 2/CU]
  gemm_bt<1, 64><<<dim3(1024 / 64, MTOT / 128), blk, 0, stream>>>(
      gbuf, wfc2T, b_fc2, x1, out, MTOT, 1024, 4096);
}

// Round 6
// 397.263 us; speedup vs baseline: 1.3156x; 1.0838x over previous
//
#include <hip/hip_runtime.h>
#include <hip/hip_bf16.h>

typedef unsigned short u16;
typedef unsigned int u32;
typedef short bf16x8 __attribute__((ext_vector_type(8)));
typedef float f32x4 __attribute__((ext_vector_type(4)));

// Problem constants: B=2, L=2048, D=1024, H=16, hd=64, INNER=4096
#define SEQ 2048
#define DM 1024
#define NH 16
#define HD 64
#define INNER 4096
#define MTOT 4096  // B*L
#define QKV_ELEMS 4194304  // 2*16*2048*64

static __device__ __forceinline__ u16 f2bf(float f) {
  u32 u = __float_as_uint(f);
  u = (u + 0x7fffu + ((u >> 16) & 1u)) >> 16;
  return (u16)u;
}

static __device__ __forceinline__ void async_copy16(void* lds, const void* g) {
  __builtin_amdgcn_global_load_lds(
      (const __attribute__((address_space(1))) u32*)g,
      (__attribute__((address_space(3))) u32*)lds, 16, 0, 0);
}

#define MFMA16(a, b, c) __builtin_amdgcn_mfma_f32_16x16x32_bf16(a, b, c, 0, 0, 0)

// ---------------- transpose + fp32->bf16 cast: dst[n][k] = bf16(src[k][n]) ----
__global__ __launch_bounds__(256) void transpose_cast(
    const float* __restrict__ src, u16* __restrict__ dst, int K, int N) {
  __shared__ float tile[32][33];
  int bx = blockIdx.x;  // along N
  int by = blockIdx.y;  // along K
  int t = threadIdx.x;
  int tr = t >> 5, tc = t & 31;
#pragma unroll
  for (int i = 0; i < 4; ++i) {
    int r = by * 32 + tr + i * 8;
    int c = bx * 32 + tc;
    tile[tr + i * 8][tc] = src[(size_t)r * N + c];
  }
  __syncthreads();
#pragma unroll
  for (int i = 0; i < 4; ++i) {
    int n = bx * 32 + tr + i * 8;
    int kk = by * 32 + tc;
    dst[(size_t)n * K + kk] = f2bf(tile[tc][tr + i * 8]);
  }
}

// ---------------- LayerNorm (fp32 in, bf16 out), one row per block ----------
__global__ __launch_bounds__(256) void ln_kernel(
    const float* __restrict__ x, const float* __restrict__ g,
    const float* __restrict__ b, u16* __restrict__ out) {
  int row = blockIdx.x, t = threadIdx.x;
  const float* xr = x + (size_t)row * DM;
  float4 v = *(const float4*)(xr + t * 4);
  float s = v.x + v.y + v.z + v.w;
  float ss = v.x * v.x + v.y * v.y + v.z * v.z + v.w * v.w;
#pragma unroll
  for (int d = 1; d < 64; d <<= 1) {
    s += __shfl_xor(s, d);
    ss += __shfl_xor(ss, d);
  }
  __shared__ float red[8];
  int w = t >> 6, lane = t & 63;
  if (lane == 0) { red[w] = s; red[4 + w] = ss; }
  __syncthreads();
  s = red[0] + red[1] + red[2] + red[3];
  ss = red[4] + red[5] + red[6] + red[7];
  float mu = s * (1.f / DM);
  float var = ss * (1.f / DM) - mu * mu;
  float rstd = rsqrtf(var + 1e-5f);
  float4 gv = *(const float4*)(g + t * 4);
  float4 bv = *(const float4*)(b + t * 4);
  u32 p0 = (u32)f2bf((v.x - mu) * rstd * gv.x + bv.x) |
           ((u32)f2bf((v.y - mu) * rstd * gv.y + bv.y) << 16);
  u32 p1 = (u32)f2bf((v.z - mu) * rstd * gv.z + bv.z) |
           ((u32)f2bf((v.w - mu) * rstd * gv.w + bv.w) << 16);
  uint2 pk; pk.x = p0; pk.y = p1;
  *(uint2*)(out + (size_t)row * DM + t * 4) = pk;
}

// ---------------- GEMM: C[M][N] = A[M][K] (bf16) @ Bt[N][K]^T (bf16) --------
// 128xBN tile (BN=128 or 64), BK=32, 4 waves (2x2). Double-buffered LDS,
// 2-phase prefetch: issue next K-tile's global_load_lds BEFORE computing
// current tile; single trailing __syncthreads per step.
// EPI 0: +bias, scatter to q(x0.125*log2e)/k/(v transposed) bf16
// EPI 1: +bias +resid -> fp32
// EPI 2: +bias, exact GELU -> bf16
template <int EPI, int BN>
__global__ __launch_bounds__(256) void gemm_bt(
    const u16* __restrict__ A, const u16* __restrict__ Bt,
    const float* __restrict__ bias, const float* __restrict__ resid,
    void* __restrict__ outp, int M, int N, int K) {
  constexpr int NF = BN / 32;  // N-frags per wave (2x2 wave grid)
  __shared__ u16 As[2][128 * 32];
  __shared__ u16 Bs[2][BN * 32];
  int t = threadIdx.x;
  int lane = t & 63, w = t >> 6;
  int lo = lane & 15, hi = lane >> 4;
  int wr = w >> 1, wc = w & 1;
  int m0 = blockIdx.y * 128, n0 = blockIdx.x * BN;

  f32x4 acc[4][NF];
#pragma unroll
  for (int i = 0; i < 4; ++i)
#pragma unroll
    for (int j = 0; j < NF; ++j) acc[i][j] = f32x4{0.f, 0.f, 0.f, 0.f};

  const u16* gA = A + (size_t)(m0 + (t >> 2)) * K + (t & 3) * 8;
  const u16* gB = Bt + (size_t)(n0 + (t >> 2)) * K + (t & 3) * 8;

  auto STAGE = [&](int buf, int kt) {
    char* lA = (char*)(&As[buf][0]) + w * 1024;
    char* lB = (char*)(&Bs[buf][0]) + w * 1024;
    async_copy16(lA, gA + kt * 32);
    async_copy16(lA + 4096, gA + (size_t)64 * K + kt * 32);
    async_copy16(lB, gB + kt * 32);
    if constexpr (BN == 128)
      async_copy16(lB + 4096, gB + (size_t)64 * K + kt * 32);
  };

  int nk = K >> 5;
  int buf = 0;
  STAGE(0, 0);
  __syncthreads();  // drains vmcnt, tile 0 ready

  for (int kt = 0; kt < nk; ++kt) {
    if (kt + 1 < nk) STAGE(buf ^ 1, kt + 1);  // prefetch overlaps compute
    bf16x8 af[4], bq[NF];
#pragma unroll
    for (int f = 0; f < 4; ++f)
      af[f] = *(const bf16x8*)(&As[buf][(wr * 64 + f * 16 + lo) * 32 + hi * 8]);
#pragma unroll
    for (int j = 0; j < NF; ++j)
      bq[j] = *(const bf16x8*)(&Bs[buf][(wc * (BN / 2) + j * 16 + lo) * 32 + hi * 8]);
#pragma unroll
    for (int i = 0; i < 4; ++i)
#pragma unroll
      for (int j = 0; j < NF; ++j)
        acc[i][j] = MFMA16(af[i], bq[j], acc[i][j]);
    __syncthreads();  // one barrier/step: drains prefetch + read-write hazard
    buf ^= 1;
  }

#pragma unroll
  for (int i = 0; i < 4; ++i) {
#pragma unroll
    for (int j = 0; j < NF; ++j) {
      int col = n0 + wc * (BN / 2) + j * 16 + lo;
#pragma unroll
      for (int r = 0; r < 4; ++r) {
        int m = m0 + wr * 64 + i * 16 + hi * 4 + r;
        float val = acc[i][j][r];
        if constexpr (EPI == 0) {
          val += bias[col];
          int which = col >> 10;
          int h = (col >> 6) & 15, d = col & 63;
          int b = m >> 11, l = m & 2047;
          size_t bh = (size_t)(b * NH + h);
          u16* qp = (u16*)outp;
          if (which == 0)
            qp[(bh * SEQ + l) * HD + d] = f2bf(val * 0.18033688011112043f);
          else if (which == 1)
            (qp + QKV_ELEMS)[(bh * SEQ + l) * HD + d] = f2bf(val);
          else
            (qp + 2 * QKV_ELEMS)[(bh * HD + d) * SEQ + l] = f2bf(val);
        } else if constexpr (EPI == 1) {
          val += bias[col] + resid[(size_t)m * N + col];
          ((float*)outp)[(size_t)m * N + col] = val;
        } else {
          val += bias[col];
          val = 0.5f * val * (1.0f + erff(val * 0.7071067811865476f));
          ((u16*)outp)[(size_t)m * N + col] = f2bf(val);
        }
      }
    }
  }
}

// ---------------- causal flash attention v3 ---------------------------------
// Balanced pairing: grid (16, 32); block bx does q-tiles (31-bx) then bx.
// 4 waves x 16 q-rows. Changes vs v2:
//  * K/V double-buffered in LDS via global_load_lds (linear dest) with
//    inverse-swizzled GLOBAL source; swizzled read side unchanged.
//    Prefetch next tile before compute -> ONE barrier per k-step.
//  * psum folded into PV via MFMA with all-ones B-frag (o_sum accumulator);
//    bf16-P bias cancels between numerator and denominator.
//  * defer-max (THR=8, exp2 domain): skip rescale when max growth <= 8.
//  * Ps: [16][64] per wave, XOR-swizzled (2-way max on write & read).
// q pre-scaled by 0.125*log2e; v stored transposed vt[bh][d][l].
__global__ __launch_bounds__(256) void attn_kernel(
    const u16* __restrict__ q, const u16* __restrict__ k,
    const u16* __restrict__ vt, u16* __restrict__ o) {
  int bx = blockIdx.x, bh = blockIdx.y;
  int t = threadIdx.x;
  int lane = t & 63, w = t >> 6;
  int lo = lane & 15, hi = lane >> 4;

  __shared__ u16 Ks[2][4096];  // [buf][64 rows x 64 cols], swizzled granules
  __shared__ u16 Vs[2][4096];
  __shared__ u16 Ps[4][1024];  // per-wave 16 rows x 64 cols, swizzled

  const char* kg = (const char*)(k + (size_t)bh * SEQ * HD);
  const char* vg = (const char*)(vt + (size_t)bh * HD * SEQ);
  int b = bh >> 4, h = bh & 15;

  u32 sw = (u32)((lo & 7) << 4);  // read-side XOR swizzle (row&7 == lo&7)

  // staging lane constants: granule g = p*256 + w*64 + lane; r=g>>3, c=g&7
  int koff[2], voff[2];
#pragma unroll
  for (int p = 0; p < 2; ++p) {
    int g = p * 256 + w * 64 + lane;
    int r = g >> 3, c = g & 7;
    int cs = c ^ (r & 7);  // inverse swizzle on global source
    koff[p] = r * 128 + cs * 16;   // K row stride 128B
    voff[p] = r * 4096 + cs * 16;  // V row stride 4096B (vt[d][l])
  }

  bf16x8 ones;
#pragma unroll
  for (int i = 0; i < 8; ++i) ones[i] = (short)0x3F80;  // bf16 1.0

#pragma unroll 1
  for (int pass = 0; pass < 2; ++pass) {
    int qt = pass == 0 ? (31 - bx) : bx;

    int qrow = qt * 64 + w * 16 + lo;
    const u16* qbase = q + ((size_t)bh * SEQ + qrow) * HD;
    bf16x8 qf0 = *(const bf16x8*)(qbase + hi * 8);
    bf16x8 qf1 = *(const bf16x8*)(qbase + 32 + hi * 8);

    f32x4 o_acc[4];
#pragma unroll
    for (int df = 0; df < 4; ++df) o_acc[df] = f32x4{0.f, 0.f, 0.f, 0.f};
    f32x4 o_sum = f32x4{0.f, 0.f, 0.f, 0.f};
    float m_run[4] = {-INFINITY, -INFINITY, -INFINITY, -INFINITY};

    auto STAGE = [&](int bb, int kt) {
#pragma unroll
      for (int p = 0; p < 2; ++p) {
        async_copy16((char*)&Ks[bb][0] + p * 4096 + w * 1024,
                     kg + (size_t)kt * 8192 + koff[p]);
        async_copy16((char*)&Vs[bb][0] + p * 4096 + w * 1024,
                     vg + (size_t)kt * 128 + voff[p]);
      }
    };

    int buf = 0;
    STAGE(0, 0);
    __syncthreads();  // drain: tile 0 ready

    for (int kt = 0; kt <= qt; ++kt) {
      if (kt < qt) STAGE(buf ^ 1, kt + 1);  // prefetch under compute

      // S = Q K^T (16x64 per wave)
      f32x4 s[4];
#pragma unroll
      for (int cf = 0; cf < 4; ++cf) {
        s[cf] = f32x4{0.f, 0.f, 0.f, 0.f};
        u32 ro = (u32)((cf * 16 + lo) * 128);
        bf16x8 kf0 = *(const bf16x8*)((char*)&Ks[buf][0] + ((ro + hi * 16) ^ sw));
        bf16x8 kf1 =
            *(const bf16x8*)((char*)&Ks[buf][0] + ((ro + 64 + hi * 16) ^ sw));
        s[cf] = MFMA16(qf0, kf0, s[cf]);
        s[cf] = MFMA16(qf1, kf1, s[cf]);
      }

      if (kt == qt) {
#pragma unroll
        for (int cf = 0; cf < 4; ++cf)
#pragma unroll
          for (int r = 0; r < 4; ++r) {
            int kcol = kt * 64 + cf * 16 + lo;
            int qr = qt * 64 + w * 16 + hi * 4 + r;
            if (kcol > qr) s[cf][r] = -INFINITY;
          }
      }

      // per-row max (over cf in-reg, over 16 lo-lanes via shfl)
      float pmax[4];
#pragma unroll
      for (int r = 0; r < 4; ++r) {
        float v = fmaxf(fmaxf(s[0][r], s[1][r]), fmaxf(s[2][r], s[3][r]));
        v = fmaxf(v, __shfl_xor(v, 1));
        v = fmaxf(v, __shfl_xor(v, 2));
        v = fmaxf(v, __shfl_xor(v, 4));
        v = fmaxf(v, __shfl_xor(v, 8));
        pmax[r] = v;
      }

      // defer-max: rescale only if some row grew by > 8 (exp2 domain)
      int small = (pmax[0] <= m_run[0] + 8.f) & (pmax[1] <= m_run[1] + 8.f) &
                  (pmax[2] <= m_run[2] + 8.f) & (pmax[3] <= m_run[3] + 8.f);
      if (!__all(small)) {
#pragma unroll
        for (int r = 0; r < 4; ++r) {
          float mnew = fmaxf(m_run[r], pmax[r]);
          float a = exp2f(m_run[r] - mnew);
          m_run[r] = mnew;
          o_sum[r] *= a;
#pragma unroll
          for (int df = 0; df < 4; ++df) o_acc[df][r] *= a;
        }
      }

      // P = exp2(s - m_run), store bf16 (trunc) to swizzled Ps
#pragma unroll
      for (int r = 0; r < 4; ++r) {
        int prow = hi * 4 + r;
        u32 pbase = (u32)(prow * 128);
        u32 psw = (u32)((prow & 7) << 4);
#pragma unroll
        for (int cf = 0; cf < 4; ++cf) {
          float p = exp2f(s[cf][r] - m_run[r]);
          u32 boff = pbase + (((u32)((cf * 16 + lo) * 2)) ^ psw);
          *(u16*)((char*)&Ps[w][0] + boff) = (u16)(__float_as_uint(p) >> 16);
        }
      }

      // O += P V ; row-sum via MFMA with ones B-frag
#pragma unroll
      for (int ks = 0; ks < 2; ++ks) {
        u32 rboff = (u32)(lo * 128 + (((u32)(ks * 64 + hi * 16)) ^ sw));
        bf16x8 pf = *(const bf16x8*)((char*)&Ps[w][0] + rboff);
#pragma unroll
        for (int df = 0; df < 4; ++df) {
          u32 ro = (u32)((df * 16 + lo) * 128);
          bf16x8 vf = *(const bf16x8*)((char*)&Vs[buf][0] +
                                       ((ro + ks * 64 + hi * 16) ^ sw));
          o_acc[df] = MFMA16(pf, vf, o_acc[df]);
        }
        o_sum = MFMA16(pf, ones, o_sum);
      }

      __syncthreads();  // drains prefetch; guards K/V buf reuse
      buf ^= 1;
    }

#pragma unroll
    for (int df = 0; df < 4; ++df) {
#pragma unroll
      for (int r = 0; r < 4; ++r) {
        float val = o_acc[df][r] / o_sum[r];
        int orow = qt * 64 + w * 16 + hi * 4 + r;
        size_t oidx = ((size_t)b * SEQ + orow) * DM + h * HD + df * 16 + lo;
        o[oidx] = f2bf(val);
      }
    }
  }
}

// ---------------- launch ----------------------------------------------------
extern "C" void kernel_launch(void* const* d_in, const int* in_sizes, int n_in,
                              void* d_out, int out_size, void* d_ws,
                              size_t ws_size, hipStream_t stream) {
  const float* x = (const float*)d_in[0];
  const float* w_qkv = (const float*)d_in[1];
  const float* b_qkv = (const float*)d_in[2];
  const float* w_out = (const float*)d_in[3];
  const float* b_out = (const float*)d_in[4];
  const float* w_fc1 = (const float*)d_in[5];
  const float* b_fc1 = (const float*)d_in[6];
  const float* w_fc2 = (const float*)d_in[7];
  const float* b_fc2 = (const float*)d_in[8];
  const float* ln1_g = (const float*)d_in[9];
  const float* ln1_b = (const float*)d_in[10];
  const float* ln2_g = (const float*)d_in[11];
  const float* ln2_b = (const float*)d_in[12];
  float* out = (float*)d_out;

  char* ws = (char*)d_ws;
  const size_t MB = 1u << 20;
  u16* hb = (u16*)(ws + 0);            // 8 MB (LN1 out, reused for LN2 out)
  u16* wqkvT = (u16*)(ws + 8 * MB);    // 6 MB
  u16* woutT = (u16*)(ws + 14 * MB);   // 2 MB
  u16* wfc1T = (u16*)(ws + 16 * MB);   // 8 MB
  u16* wfc2T = (u16*)(ws + 24 * MB);   // 8 MB
  u16* qb = (u16*)(ws + 32 * MB);      // q 8MB, k 8MB, vt 8MB contiguous
  u16* attn_o = (u16*)(ws + 56 * MB);  // 8 MB
  float* x1 = (float*)(ws + 64 * MB);  // 16 MB
  u16* gbuf = (u16*)(ws + 32 * MB);    // 32 MB, aliases q/k/vt/attn_o (dead)

  dim3 blk(256);

  // weights -> bf16, transposed
  transpose_cast<<<dim3(3072 / 32, 1024 / 32), blk, 0, stream>>>(w_qkv, wqkvT, 1024, 3072);
  transpose_cast<<<dim3(1024 / 32, 1024 / 32), blk, 0, stream>>>(w_out, woutT, 1024, 1024);
  transpose_cast<<<dim3(4096 / 32, 1024 / 32), blk, 0, stream>>>(w_fc1, wfc1T, 1024, 4096);
  transpose_cast<<<dim3(1024 / 32, 4096 / 32), blk, 0, stream>>>(w_fc2, wfc2T, 4096, 1024);

  // LN1
  ln_kernel<<<MTOT, blk, 0, stream>>>(x, ln1_g, ln1_b, hb);

  // QKV projection, scatter to q/k/vt
  gemm_bt<0, 128><<<dim3(3072 / 128, MTOT / 128), blk, 0, stream>>>(
      hb, wqkvT, b_qkv, nullptr, qb, MTOT, 3072, 1024);

  // causal attention (balanced q-tile pairing, v3)
  attn_kernel<<<dim3(16, 32), blk, 0, stream>>>(
      qb, qb + QKV_ELEMS, qb + 2 * QKV_ELEMS, attn_o);

  // out projection + residual -> x1 (fp32)   [BN=64: 512 blocks = 2/CU]
  gemm_bt<1, 64><<<dim3(1024 / 64, MTOT / 128), blk, 0, stream>>>(
      attn_o, woutT, b_out, x, x1, MTOT, 1024, 1024);

  // LN2
  ln_kernel<<<MTOT, blk, 0, stream>>>(x1, ln2_g, ln2_b, hb);

  // FC1 + GELU -> bf16
  gemm_bt<2, 128><<<dim3(4096 / 128, MTOT / 128), blk, 0, stream>>>(
      hb, wfc1T, b_fc1, nullptr, gbuf, MTOT, 4096, 1024);

  // FC2 + residual -> out (fp32)   [BN=64: 512 blocks = 2/CU]
  gemm_bt<1, 64><<<dim3(1024 / 64, MTOT / 128), blk, 0, stream>>>(
      gbuf, wfc2T, b_fc2, x1, out, MTOT, 1024, 4096);
}